// Round 6
// baseline (1445.889 us; speedup 1.0000x reference)
//
#include <hip/hip_runtime.h>

// APPNP propagation - ROUND 20: multi-node waves (8 nodes/wave, pipelined).
// R19 post-mortem: unpadded 100-B rows cost +40% FETCH (2.5 lines/row vs 2)
// -> reverted to padded GS=64 plane. But R19 sustained 2.67 TB/s L2-miss
// traffic vs R18's 2.0 -> R18 was NOT fabric-bound. Wave-lifetime math:
// 1 node/wave = serial {col preload ~0.8us -> 16 gathers ~0.8 -> epilogue
// ~0.8} ~2.6us x 100k waves / ~5.6k resident = ~46us =~ measured 53.7.
// Avg deg 16 -> the 16-deep unroll runs ONCE; fixed overhead dominates.
// Fix: 8 nodes per wave. Segments are contiguous -> one col preload per 64
// edges (8x amortized); gathers pipelined in 16-edge A/B batches ACROSS node
// boundaries (16-32 in flight); per-node flush is cheap (lane=feature, no
// reduce) using preloaded boundaries/norms/f0-rows; all arrays
// constant-indexed (no scratch), flush via switch(k).
// Predict: FETCH ~95 MB, dur 53.7 -> 36-44 us/iter, total ~530-570.
// Decision: if >=50 us/iter, wave-lifetime model wrong -> pivot to byte cuts.
//
// Math: feat_{k+1} = 0.9 * norm * (A_T (feat_k * norm)) + 0.1 * feat_0,
// norm = clip(indeg,1)^(-0.5), indeg over dst (d_in[1]=src, d_in[2]=dst).
//
// Build (atomic-free, R19 form): LDS-histogram counting sort, XCD-aligned
// ranges, int4/longlong2 streams. counts (12.8 MB) overlays d_out during
// build. Plane bf16 GS=64 (12.8 MB): g0 -> P_do(d_out); odd its
// P_do -> P_ws(ws); even its P_ws -> P_do; it10 reads P_ws, writes final
// fp32 over d_out.

#define NN 100000
#define EE 1600000
#define DD 50
#define GS 64
#define KK 10
#define NBLK 391
#define SLICES 32
#define RANGES 8
#define NR (NN / RANGES)   // 12500 nodes per range
#define ES (EE / SLICES)   // 50000 edges per slice

__device__ __forceinline__ float feat_at(const void* f, long long i, int ft) {
    if (ft) return ((const float*)f)[i];
    unsigned int w = ((unsigned int)((const unsigned short*)f)[i]) << 16;
    return __uint_as_float(w);
}

__device__ __forceinline__ float bf16_ld(const unsigned short* p, int i) {
    unsigned int w = ((unsigned int)p[i]) << 16;
    return __uint_as_float(w);
}

__device__ __forceinline__ unsigned short bf16_st(float x) {
    unsigned int u = __float_as_uint(x);
    unsigned int r = (u + 0x7FFF + ((u >> 16) & 1)) >> 16; // round-nearest-even
    return (unsigned short)r;
}

// ---- build kernel: LDS-histogram count (phase 0) / scatter (phase 1) ----
__global__ __launch_bounds__(512) void APPNPConv_62199716381208_build(
        const void* srcp, const void* dstp, const void* featp,
        unsigned int* counts, int* col_idx, int* flag, int phase) {
    __shared__ unsigned int hist[NR]; // 50 KB
    const int tid = threadIdx.x;
    const int r = blockIdx.x & 7;   // XCD-aligned: all slices of range r on one XCD
    const int s = blockIdx.x >> 3;  // slice 0..31
    const int r0 = r * NR;
    const long long e0 = (long long)s * ES;

    if (phase == 0) {
        const int* a = (const int*)dstp;
        const int is64 = ((a[1] | a[3] | a[5] | a[7] | a[9] | a[11] | a[13] | a[15]) == 0);
        if (blockIdx.x == 0 && tid == 0) {
            flag[0] = is64;
            const unsigned short* w = (const unsigned short*)featp;
            int isf32 = 0;
            for (int k = 0; k < 64; ++k) {
                unsigned int b = ((unsigned int)w[k]) << 16;
                float ax = fabsf(__uint_as_float(b));
                if (!(ax < 100.0f)) isf32 = 1;
            }
            flag[1] = isf32;
        }
        for (int i = tid; i < NR; i += 512) hist[i] = 0u;
        __syncthreads();
        if (is64) {
            const longlong2* dp = (const longlong2*)((const long long*)dstp + e0);
            for (int i = tid; i < ES / 4; i += 512) {
                longlong2 d0 = dp[2 * i];
                longlong2 d1 = dp[2 * i + 1];
                unsigned int a0 = (unsigned int)((int)d0.x - r0);
                unsigned int a1 = (unsigned int)((int)d0.y - r0);
                unsigned int a2 = (unsigned int)((int)d1.x - r0);
                unsigned int a3 = (unsigned int)((int)d1.y - r0);
                if (a0 < (unsigned int)NR) atomicAdd(&hist[a0], 1u);
                if (a1 < (unsigned int)NR) atomicAdd(&hist[a1], 1u);
                if (a2 < (unsigned int)NR) atomicAdd(&hist[a2], 1u);
                if (a3 < (unsigned int)NR) atomicAdd(&hist[a3], 1u);
            }
        } else {
            const int4* dp = (const int4*)((const int*)dstp + e0);
            for (int i = tid; i < ES / 4; i += 512) {
                int4 dd = dp[i];
                unsigned int a0 = (unsigned int)(dd.x - r0);
                unsigned int a1 = (unsigned int)(dd.y - r0);
                unsigned int a2 = (unsigned int)(dd.z - r0);
                unsigned int a3 = (unsigned int)(dd.w - r0);
                if (a0 < (unsigned int)NR) atomicAdd(&hist[a0], 1u);
                if (a1 < (unsigned int)NR) atomicAdd(&hist[a1], 1u);
                if (a2 < (unsigned int)NR) atomicAdd(&hist[a2], 1u);
                if (a3 < (unsigned int)NR) atomicAdd(&hist[a3], 1u);
            }
        }
        __syncthreads();
        for (int i = tid; i < NR; i += 512)
            counts[(size_t)s * NN + r0 + i] = hist[i];
    } else {
        const int is64 = flag[0];
        for (int i = tid; i < NR; i += 512)
            hist[i] = counts[(size_t)s * NN + r0 + i];
        __syncthreads();
        if (is64) {
            const longlong2* dp = (const longlong2*)((const long long*)dstp + e0);
            const longlong2* sp = (const longlong2*)((const long long*)srcp + e0);
            for (int i = tid; i < ES / 4; i += 512) {
                longlong2 d0 = dp[2 * i];
                longlong2 d1 = dp[2 * i + 1];
                longlong2 s0 = sp[2 * i];
                longlong2 s1 = sp[2 * i + 1];
                unsigned int a0 = (unsigned int)((int)d0.x - r0);
                unsigned int a1 = (unsigned int)((int)d0.y - r0);
                unsigned int a2 = (unsigned int)((int)d1.x - r0);
                unsigned int a3 = (unsigned int)((int)d1.y - r0);
                if (a0 < (unsigned int)NR) {
                    unsigned int pos = atomicAdd(&hist[a0], 1u);
                    int c = (int)s0.x;
                    if (pos < (unsigned int)EE)
                        col_idx[pos] = ((unsigned int)c < (unsigned int)NN) ? c : 0;
                }
                if (a1 < (unsigned int)NR) {
                    unsigned int pos = atomicAdd(&hist[a1], 1u);
                    int c = (int)s0.y;
                    if (pos < (unsigned int)EE)
                        col_idx[pos] = ((unsigned int)c < (unsigned int)NN) ? c : 0;
                }
                if (a2 < (unsigned int)NR) {
                    unsigned int pos = atomicAdd(&hist[a2], 1u);
                    int c = (int)s1.x;
                    if (pos < (unsigned int)EE)
                        col_idx[pos] = ((unsigned int)c < (unsigned int)NN) ? c : 0;
                }
                if (a3 < (unsigned int)NR) {
                    unsigned int pos = atomicAdd(&hist[a3], 1u);
                    int c = (int)s1.y;
                    if (pos < (unsigned int)EE)
                        col_idx[pos] = ((unsigned int)c < (unsigned int)NN) ? c : 0;
                }
            }
        } else {
            const int4* dp = (const int4*)((const int*)dstp + e0);
            const int4* sp = (const int4*)((const int*)srcp + e0);
            for (int i = tid; i < ES / 4; i += 512) {
                int4 dd = dp[i];
                int4 ss = sp[i];
                unsigned int a0 = (unsigned int)(dd.x - r0);
                unsigned int a1 = (unsigned int)(dd.y - r0);
                unsigned int a2 = (unsigned int)(dd.z - r0);
                unsigned int a3 = (unsigned int)(dd.w - r0);
                if (a0 < (unsigned int)NR) {
                    unsigned int pos = atomicAdd(&hist[a0], 1u);
                    if (pos < (unsigned int)EE)
                        col_idx[pos] = ((unsigned int)ss.x < (unsigned int)NN) ? ss.x : 0;
                }
                if (a1 < (unsigned int)NR) {
                    unsigned int pos = atomicAdd(&hist[a1], 1u);
                    if (pos < (unsigned int)EE)
                        col_idx[pos] = ((unsigned int)ss.y < (unsigned int)NN) ? ss.y : 0;
                }
                if (a2 < (unsigned int)NR) {
                    unsigned int pos = atomicAdd(&hist[a2], 1u);
                    if (pos < (unsigned int)EE)
                        col_idx[pos] = ((unsigned int)ss.z < (unsigned int)NN) ? ss.z : 0;
                }
                if (a3 < (unsigned int)NR) {
                    unsigned int pos = atomicAdd(&hist[a3], 1u);
                    if (pos < (unsigned int)EE)
                        col_idx[pos] = ((unsigned int)ss.w < (unsigned int)NN) ? ss.w : 0;
                }
            }
        }
    }
}

// ---- main kernel ----
// Phases: 2 totals+norm | 3 scan | 4 rowptr+slice bases | 6 g0 | 7 gather.
__global__ __launch_bounds__(512) void APPNPConv_62199716381208_kernel(
        const void* featp, const void* srcp, const void* dstp,
        int* deg, float* norm, int* row_ptr, int* col_idx, int* bsum, int* flag,
        unsigned int* counts,
        const unsigned short* gin, unsigned short* gout, float* outp,
        int phase, int last) {
    __shared__ int sh[512];
    const int tid = threadIdx.x;

    if (phase == 2) {
        int n = blockIdx.x * 256 + tid;
        int total = 0;
        if (n < NN) {
            #pragma unroll 4
            for (int s = 0; s < SLICES; ++s)
                total += (int)counts[(size_t)s * NN + n];
            deg[n] = total;
            norm[n] = rsqrtf((float)(total < 1 ? 1 : total));
        }
        sh[tid] = total;
        __syncthreads();
        for (int off = 128; off > 0; off >>= 1) {
            if (tid < off) sh[tid] += sh[tid + off];
            __syncthreads();
        }
        if (tid == 0) bsum[blockIdx.x] = sh[0];
        return;
    }
    if (phase == 3) {
        int v = (tid < NBLK) ? bsum[tid] : 0;
        sh[tid] = v;
        __syncthreads();
        for (int off = 1; off < 512; off <<= 1) {
            int x = (tid >= off) ? sh[tid - off] : 0;
            __syncthreads();
            sh[tid] += x;
            __syncthreads();
        }
        if (tid < NBLK) bsum[tid] = sh[tid] - v;
        return;
    }
    if (phase == 4) {
        int i = blockIdx.x * 256 + tid;
        int v = (i < NN) ? deg[i] : 0;
        sh[tid] = v;
        __syncthreads();
        for (int off = 1; off < 256; off <<= 1) {
            int x = (tid >= off) ? sh[tid - off] : 0;
            __syncthreads();
            sh[tid] += x;
            __syncthreads();
        }
        int excl = sh[tid] - v + bsum[blockIdx.x];
        if (i < NN) {
            row_ptr[i] = excl;
            unsigned int run = (unsigned int)excl;
            for (int s = 0; s < SLICES; ++s) {
                size_t o = (size_t)s * NN + i;
                unsigned int c = counts[o];
                counts[o] = run;
                run += c;
            }
        }
        if (i == 0) row_ptr[NN] = EE;
        return;
    }
    if (phase == 6) {
        // thread = (node v, slot d in [0,64)); write only d < 50
        int gidx = blockIdx.x * 256 + tid;
        int v = gidx >> 6;
        int d = gidx & 63;
        if (v < NN && d < DD) {
            float x = feat_at(featp, (long long)v * DD + d, flag[1]);
            gout[(v << 6) + d] = bf16_st(x * norm[v]);
        }
        return;
    }
    // phase 7: gather-propagate. One wave per EIGHT consecutive nodes.
    // Contiguous col_idx walk (1 preload / 64 edges), 16-edge A/B pipelined
    // batches across node boundaries, per-node register flush via switch.
    {
        const int lane = tid & 63;
        const int w = (blockIdx.x << 2) + (tid >> 6);
        const int v0 = w << 3;
        if (v0 >= NN) return;
        const int act = (lane < DD);
        const int ft = flag[1];

        int bl = 0;
        if (lane <= 8) bl = row_ptr[v0 + lane];
        int bnd[9];
        #pragma unroll
        for (int i = 0; i < 9; ++i) bnd[i] = __shfl(bl, i, 64);

        float nl = (lane < 8) ? norm[v0 + lane] : 0.0f;

        float f0r[8];
        #pragma unroll
        for (int i = 0; i < 8; ++i)
            f0r[i] = act ? feat_at(featp, (long long)(v0 + i) * DD + lane, ft) : 0.0f;

        const int beg = bnd[0];
        const int end = bnd[8];
        float s[4] = {0.0f, 0.0f, 0.0f, 0.0f};
        int k = 0;
        int nb = bnd[1];

#define DO_FLUSH(KK) { \
        float sum = (s[0] + s[1]) + (s[2] + s[3]); \
        s[0] = 0.0f; s[1] = 0.0f; s[2] = 0.0f; s[3] = 0.0f; \
        float nv = __shfl(nl, KK, 64); \
        float res = 0.9f * (sum * nv) + 0.1f * f0r[KK]; \
        int vtx = v0 + KK; \
        if (act) { \
            if (last) outp[(long long)vtx * DD + lane] = res; \
            else gout[(vtx << 6) + lane] = bf16_st(res * nv); \
        } }
#define FLUSH_ADV() { switch (k) { \
        case 0: DO_FLUSH(0); nb = bnd[2]; break; \
        case 1: DO_FLUSH(1); nb = bnd[3]; break; \
        case 2: DO_FLUSH(2); nb = bnd[4]; break; \
        case 3: DO_FLUSH(3); nb = bnd[5]; break; \
        case 4: DO_FLUSH(4); nb = bnd[6]; break; \
        case 5: DO_FLUSH(5); nb = bnd[7]; break; \
        case 6: DO_FLUSH(6); nb = bnd[8]; break; \
        default: DO_FLUSH(7); nb = 0x7fffffff; break; } ++k; }
#define ISSUE16(X, J) { \
        _Pragma("unroll") \
        for (int l = 0; l < 16; ++l) { \
            int c = __shfl(my, (J) + l, 64); \
            X[l] = bf16_ld(gin, (c << 6) + lane); } }
#define CONSUME16(X, J) { \
        _Pragma("unroll") \
        for (int l = 0; l < 16; ++l) { \
            if ((J) + l < cnt) { \
                int ei = base + (J) + l; \
                while (ei >= nb) FLUSH_ADV(); \
                s[l & 3] += X[l]; } } }

        float va[16], vb[16];
        for (int base = beg; base < end; base += 64) {
            int idx = base + lane;
            int my = (idx < end) ? __builtin_nontemporal_load(col_idx + idx) : 0;
            int cnt = end - base;
            if (cnt > 64) cnt = 64;
            ISSUE16(va, 0)
            if (cnt > 16) ISSUE16(vb, 16)
            CONSUME16(va, 0)
            if (cnt > 32) ISSUE16(va, 32)
            if (cnt > 16) CONSUME16(vb, 16)
            if (cnt > 48) ISSUE16(vb, 48)
            if (cnt > 32) CONSUME16(va, 32)
            if (cnt > 48) CONSUME16(vb, 48)
        }
        while (k < 8) FLUSH_ADV();

#undef DO_FLUSH
#undef FLUSH_ADV
#undef ISSUE16
#undef CONSUME16
    }
}

extern "C" void kernel_launch(void* const* d_in, const int* in_sizes, int n_in,
                              void* d_out, int out_size, void* d_ws, size_t ws_size,
                              hipStream_t stream) {
    const void* featp = d_in[0];
    const void* src = d_in[1];
    const void* dst = d_in[2];
    float* outf = (float*)d_out;
    unsigned short* P_do = (unsigned short*)d_out;   // padded plane in d_out (12.8 MB)
    unsigned int* counts = (unsigned int*)d_out;     // 12.8 MB (build only)
    size_t out_bytes = (size_t)out_size * 4;
    (void)in_sizes;

    if (n_in != 3) {
        hipMemsetAsync(d_out, 0x50, out_bytes, stream);
        return;
    }

    size_t a_deg  = (((size_t)NN * 4) + 255) / 256 * 256;
    size_t a_norm = a_deg;
    size_t a_rp   = (((size_t)(NN + 1) * 4) + 255) / 256 * 256;
    size_t a_col  = (((size_t)EE * 4) + 255) / 256 * 256;
    size_t a_bsum = (((size_t)NBLK * 4) + 255) / 256 * 256;
    size_t a_flag = 256;
    size_t a_buf  = (((size_t)NN * GS * 2) + 255) / 256 * 256; // 12.8 MB padded plane
    if (ws_size < a_deg + a_norm + a_rp + a_col + a_bsum + a_flag + a_buf ||
        out_bytes < (size_t)SLICES * NN * 4) {
        hipMemsetAsync(d_out, 0x40, out_bytes, stream);
        return;
    }
    char* p = (char*)d_ws;
    int* deg      = (int*)p;   p += a_deg;
    float* norm   = (float*)p; p += a_norm;
    int* row_ptr  = (int*)p;   p += a_rp;
    int* col_idx  = (int*)p;   p += a_col;
    int* bsum     = (int*)p;   p += a_bsum;
    int* flag     = (int*)p;   p += a_flag;
    unsigned short* P_ws = (unsigned short*)p;

    (void)hipGetLastError();

    #define LCH(grid, blk, gi, go, ph, la) \
        APPNPConv_62199716381208_kernel<<<(grid), (blk), 0, stream>>>( \
            featp, src, dst, deg, norm, row_ptr, col_idx, bsum, flag, counts, \
            (gi), (go), outf, (ph), (la))
    #define LCB(ph) \
        APPNPConv_62199716381208_build<<<SLICES * RANGES, 512, 0, stream>>>( \
            src, dst, featp, counts, col_idx, flag, (ph))

    LCB(0);                                           // phA: flags + LDS-hist counts
    LCH(NBLK, 256, P_ws, P_ws, 2, 0);                 // totals + norm
    LCH(1, 512, P_ws, P_ws, 3, 0);                    // scan
    LCH(NBLK, 256, P_ws, P_ws, 4, 0);                 // row_ptr + slice bases
    LCB(1);                                           // phC: LDS-cursor scatter
    LCH((NN * GS + 255) / 256, 256, P_ws, P_do, 6, 0); // g0 -> P_do (padded)

    // it odd: P_do -> P_ws ; it even: P_ws -> P_do.
    // it10 (even): reads P_ws, writes FINAL fp32 over all of d_out.
    for (int it = 1; it <= KK; ++it) {
        const unsigned short* gi = (it & 1) ? P_do : P_ws;
        unsigned short* go       = (it & 1) ? P_ws : P_do;
        LCH(NN / 32, 256, gi, go, 7, (it == KK) ? 1 : 0);
    }
    #undef LCH
    #undef LCB

    if (hipGetLastError() != hipSuccess) {
        hipMemsetAsync(d_out, 0xBF, out_bytes, stream);
    }
}

// Round 7
// 688.097 us; speedup vs baseline: 2.1013x; 2.1013x over previous
//
#include <hip/hip_runtime.h>

// APPNP propagation - ROUND 21: 4-node waves, VGPR-disciplined + XCD swizzle.
// R20 post-mortem: 8-node wave died of implementation, not hypothesis:
// VGPR 88 -> occupancy 19% -> 146 us/iter (FETCH 91 MB as predicted; bytes
// fine, parallelism gone). Causes: va[16]/vb[16]/f0r[8] arrays + per-edge
// while-flush control flow.
// This round amortizes per-node fixed costs (col preload, f0 stall) WITHOUT
// occupancy loss: wave owns 4 consecutive nodes; boundaries = 1 lane-load +
// 5 shfls (uniform scalars); 4 f0 rows prefetched at wave start (4 VGPR,
// latency hidden under gathers); one shared 64-edge col window (1 preload /
// ~4 segments); batches of <=8 UNCONDITIONAL loads - tail slots re-read the
// batch's row 0 (L1 hit, no extra lines) and are value-masked -> full MLP,
// zero divergent branches. Plane pads written as true zeros (phase 6 and
// phase-7 stores write all 64 slots) -> no lane masking in hot loop.
// Plus bijective XCD block swizzle (m204): col/rowptr/norm/feat/writes
// XCD-local; own-stripe plane writes become next-iter L2 hits.
// Predict: VGPR<=48, occ>=60%, FETCH ~85 MB, 53.7 -> 38-46 us/iter.
// Decision: occ recovered but >=50 us at ~85 MB -> request-service floor.
//
// Math: feat_{k+1} = 0.9 * norm * (A_T (feat_k * norm)) + 0.1 * feat_0,
// norm = clip(indeg,1)^(-0.5), indeg over dst (d_in[1]=src, d_in[2]=dst).
//
// Build (atomic-free): LDS-histogram counting sort, XCD-aligned ranges,
// int4/longlong2 streams. counts (12.8 MB) overlays d_out during build.
// Plane bf16 GS=64 (12.8 MB): g0 -> P_do(d_out); odd its P_do -> P_ws(ws);
// even its P_ws -> P_do; it10 reads P_ws, writes final fp32 over d_out.

#define NN 100000
#define EE 1600000
#define DD 50
#define GS 64
#define KK 10
#define NBLK 391
#define SLICES 32
#define RANGES 8
#define NR (NN / RANGES)   // 12500 nodes per range
#define ES (EE / SLICES)   // 50000 edges per slice

__device__ __forceinline__ float feat_at(const void* f, long long i, int ft) {
    if (ft) return ((const float*)f)[i];
    unsigned int w = ((unsigned int)((const unsigned short*)f)[i]) << 16;
    return __uint_as_float(w);
}

__device__ __forceinline__ float feat_nt(const void* f, long long i, int ft) {
    if (ft) return __builtin_nontemporal_load((const float*)f + i);
    unsigned int w = ((unsigned int)__builtin_nontemporal_load(
                         (const unsigned short*)f + i)) << 16;
    return __uint_as_float(w);
}

__device__ __forceinline__ float bf16_ld(const unsigned short* p, int i) {
    unsigned int w = ((unsigned int)p[i]) << 16;
    return __uint_as_float(w);
}

__device__ __forceinline__ unsigned short bf16_st(float x) {
    unsigned int u = __float_as_uint(x);
    unsigned int r = (u + 0x7FFF + ((u >> 16) & 1)) >> 16; // round-nearest-even
    return (unsigned short)r;
}

// ---- build kernel: LDS-histogram count (phase 0) / scatter (phase 1) ----
__global__ __launch_bounds__(512) void APPNPConv_62199716381208_build(
        const void* srcp, const void* dstp, const void* featp,
        unsigned int* counts, int* col_idx, int* flag, int phase) {
    __shared__ unsigned int hist[NR]; // 50 KB
    const int tid = threadIdx.x;
    const int r = blockIdx.x & 7;   // XCD-aligned: all slices of range r on one XCD
    const int s = blockIdx.x >> 3;  // slice 0..31
    const int r0 = r * NR;
    const long long e0 = (long long)s * ES;

    if (phase == 0) {
        const int* a = (const int*)dstp;
        const int is64 = ((a[1] | a[3] | a[5] | a[7] | a[9] | a[11] | a[13] | a[15]) == 0);
        if (blockIdx.x == 0 && tid == 0) {
            flag[0] = is64;
            const unsigned short* w = (const unsigned short*)featp;
            int isf32 = 0;
            for (int k = 0; k < 64; ++k) {
                unsigned int b = ((unsigned int)w[k]) << 16;
                float ax = fabsf(__uint_as_float(b));
                if (!(ax < 100.0f)) isf32 = 1;
            }
            flag[1] = isf32;
        }
        for (int i = tid; i < NR; i += 512) hist[i] = 0u;
        __syncthreads();
        if (is64) {
            const longlong2* dp = (const longlong2*)((const long long*)dstp + e0);
            for (int i = tid; i < ES / 4; i += 512) {
                longlong2 d0 = dp[2 * i];
                longlong2 d1 = dp[2 * i + 1];
                unsigned int a0 = (unsigned int)((int)d0.x - r0);
                unsigned int a1 = (unsigned int)((int)d0.y - r0);
                unsigned int a2 = (unsigned int)((int)d1.x - r0);
                unsigned int a3 = (unsigned int)((int)d1.y - r0);
                if (a0 < (unsigned int)NR) atomicAdd(&hist[a0], 1u);
                if (a1 < (unsigned int)NR) atomicAdd(&hist[a1], 1u);
                if (a2 < (unsigned int)NR) atomicAdd(&hist[a2], 1u);
                if (a3 < (unsigned int)NR) atomicAdd(&hist[a3], 1u);
            }
        } else {
            const int4* dp = (const int4*)((const int*)dstp + e0);
            for (int i = tid; i < ES / 4; i += 512) {
                int4 dd = dp[i];
                unsigned int a0 = (unsigned int)(dd.x - r0);
                unsigned int a1 = (unsigned int)(dd.y - r0);
                unsigned int a2 = (unsigned int)(dd.z - r0);
                unsigned int a3 = (unsigned int)(dd.w - r0);
                if (a0 < (unsigned int)NR) atomicAdd(&hist[a0], 1u);
                if (a1 < (unsigned int)NR) atomicAdd(&hist[a1], 1u);
                if (a2 < (unsigned int)NR) atomicAdd(&hist[a2], 1u);
                if (a3 < (unsigned int)NR) atomicAdd(&hist[a3], 1u);
            }
        }
        __syncthreads();
        for (int i = tid; i < NR; i += 512)
            counts[(size_t)s * NN + r0 + i] = hist[i];
    } else {
        const int is64 = flag[0];
        for (int i = tid; i < NR; i += 512)
            hist[i] = counts[(size_t)s * NN + r0 + i];
        __syncthreads();
        if (is64) {
            const longlong2* dp = (const longlong2*)((const long long*)dstp + e0);
            const longlong2* sp = (const longlong2*)((const long long*)srcp + e0);
            for (int i = tid; i < ES / 4; i += 512) {
                longlong2 d0 = dp[2 * i];
                longlong2 d1 = dp[2 * i + 1];
                longlong2 s0 = sp[2 * i];
                longlong2 s1 = sp[2 * i + 1];
                unsigned int a0 = (unsigned int)((int)d0.x - r0);
                unsigned int a1 = (unsigned int)((int)d0.y - r0);
                unsigned int a2 = (unsigned int)((int)d1.x - r0);
                unsigned int a3 = (unsigned int)((int)d1.y - r0);
                if (a0 < (unsigned int)NR) {
                    unsigned int pos = atomicAdd(&hist[a0], 1u);
                    int c = (int)s0.x;
                    if (pos < (unsigned int)EE)
                        col_idx[pos] = ((unsigned int)c < (unsigned int)NN) ? c : 0;
                }
                if (a1 < (unsigned int)NR) {
                    unsigned int pos = atomicAdd(&hist[a1], 1u);
                    int c = (int)s0.y;
                    if (pos < (unsigned int)EE)
                        col_idx[pos] = ((unsigned int)c < (unsigned int)NN) ? c : 0;
                }
                if (a2 < (unsigned int)NR) {
                    unsigned int pos = atomicAdd(&hist[a2], 1u);
                    int c = (int)s1.x;
                    if (pos < (unsigned int)EE)
                        col_idx[pos] = ((unsigned int)c < (unsigned int)NN) ? c : 0;
                }
                if (a3 < (unsigned int)NR) {
                    unsigned int pos = atomicAdd(&hist[a3], 1u);
                    int c = (int)s1.y;
                    if (pos < (unsigned int)EE)
                        col_idx[pos] = ((unsigned int)c < (unsigned int)NN) ? c : 0;
                }
            }
        } else {
            const int4* dp = (const int4*)((const int*)dstp + e0);
            const int4* sp = (const int4*)((const int*)srcp + e0);
            for (int i = tid; i < ES / 4; i += 512) {
                int4 dd = dp[i];
                int4 ss = sp[i];
                unsigned int a0 = (unsigned int)(dd.x - r0);
                unsigned int a1 = (unsigned int)(dd.y - r0);
                unsigned int a2 = (unsigned int)(dd.z - r0);
                unsigned int a3 = (unsigned int)(dd.w - r0);
                if (a0 < (unsigned int)NR) {
                    unsigned int pos = atomicAdd(&hist[a0], 1u);
                    if (pos < (unsigned int)EE)
                        col_idx[pos] = ((unsigned int)ss.x < (unsigned int)NN) ? ss.x : 0;
                }
                if (a1 < (unsigned int)NR) {
                    unsigned int pos = atomicAdd(&hist[a1], 1u);
                    if (pos < (unsigned int)EE)
                        col_idx[pos] = ((unsigned int)ss.y < (unsigned int)NN) ? ss.y : 0;
                }
                if (a2 < (unsigned int)NR) {
                    unsigned int pos = atomicAdd(&hist[a2], 1u);
                    if (pos < (unsigned int)EE)
                        col_idx[pos] = ((unsigned int)ss.z < (unsigned int)NN) ? ss.z : 0;
                }
                if (a3 < (unsigned int)NR) {
                    unsigned int pos = atomicAdd(&hist[a3], 1u);
                    if (pos < (unsigned int)EE)
                        col_idx[pos] = ((unsigned int)ss.w < (unsigned int)NN) ? ss.w : 0;
                }
            }
        }
    }
}

// ---- main kernel ----
// Phases: 2 totals+norm | 3 scan | 4 rowptr+slice bases | 6 g0 | 7 gather.
__global__ __launch_bounds__(512) void APPNPConv_62199716381208_kernel(
        const void* featp, const void* srcp, const void* dstp,
        int* deg, float* norm, int* row_ptr, int* col_idx, int* bsum, int* flag,
        unsigned int* counts,
        const unsigned short* gin, unsigned short* gout, float* outp,
        int phase, int last) {
    __shared__ int sh[512];
    const int tid = threadIdx.x;

    if (phase == 2) {
        int n = blockIdx.x * 256 + tid;
        int total = 0;
        if (n < NN) {
            #pragma unroll 4
            for (int s = 0; s < SLICES; ++s)
                total += (int)counts[(size_t)s * NN + n];
            deg[n] = total;
            norm[n] = rsqrtf((float)(total < 1 ? 1 : total));
        }
        sh[tid] = total;
        __syncthreads();
        for (int off = 128; off > 0; off >>= 1) {
            if (tid < off) sh[tid] += sh[tid + off];
            __syncthreads();
        }
        if (tid == 0) bsum[blockIdx.x] = sh[0];
        return;
    }
    if (phase == 3) {
        int v = (tid < NBLK) ? bsum[tid] : 0;
        sh[tid] = v;
        __syncthreads();
        for (int off = 1; off < 512; off <<= 1) {
            int x = (tid >= off) ? sh[tid - off] : 0;
            __syncthreads();
            sh[tid] += x;
            __syncthreads();
        }
        if (tid < NBLK) bsum[tid] = sh[tid] - v;
        return;
    }
    if (phase == 4) {
        int i = blockIdx.x * 256 + tid;
        int v = (i < NN) ? deg[i] : 0;
        sh[tid] = v;
        __syncthreads();
        for (int off = 1; off < 256; off <<= 1) {
            int x = (tid >= off) ? sh[tid - off] : 0;
            __syncthreads();
            sh[tid] += x;
            __syncthreads();
        }
        int excl = sh[tid] - v + bsum[blockIdx.x];
        if (i < NN) {
            row_ptr[i] = excl;
            unsigned int run = (unsigned int)excl;
            for (int s = 0; s < SLICES; ++s) {
                size_t o = (size_t)s * NN + i;
                unsigned int c = counts[o];
                counts[o] = run;
                run += c;
            }
        }
        if (i == 0) row_ptr[NN] = EE;
        return;
    }
    if (phase == 6) {
        // thread = (node v, slot d in [0,64)); pad slots written as ZERO
        int gidx = blockIdx.x * 256 + tid;
        int v = gidx >> 6;
        int d = gidx & 63;
        if (v < NN) {
            unsigned short val = 0;
            if (d < DD) {
                float x = feat_at(featp, (long long)v * DD + d, flag[1]);
                val = bf16_st(x * norm[v]);
            }
            gout[(v << 6) + d] = val;
        }
        return;
    }
    // phase 7: gather-propagate. One wave per FOUR consecutive nodes.
    // Shared 64-edge col window; batches of <=8 unconditional loads (tail
    // re-reads batch row 0 - L1 hit - value-masked); pads are zeros so no
    // lane masking in the hot loop. f0 rows prefetched at wave start.
    {
        const int lane = tid & 63;
        // bijective XCD swizzle (m204)
        const int nwg = gridDim.x;
        const int xcd = blockIdx.x & 7;
        const int bpos = blockIdx.x >> 3;
        const int q = nwg >> 3, rr = nwg & 7;
        const int sb = (xcd < rr ? xcd * (q + 1) : rr * (q + 1) + (xcd - rr) * q) + bpos;
        const int v0 = (sb << 4) + ((tid >> 6) << 2);
        if (v0 >= NN) return;
        const int act = (lane < DD);
        const int ft = flag[1];

        int bl = 0;
        if (lane <= 4) bl = row_ptr[v0 + lane];
        const int b1 = __shfl(bl, 1, 64);
        const int b2 = __shfl(bl, 2, 64);
        const int b3 = __shfl(bl, 3, 64);
        const int b4 = __shfl(bl, 4, 64);
        const int b0 = __shfl(bl, 0, 64);
        float nl = (lane < 4) ? norm[v0 + lane] : 0.0f;

        // prefetch the 4 f0 rows (latency hides under gathers)
        float f0a = act ? feat_nt(featp, (long long)(v0 + 0) * DD + lane, ft) : 0.0f;
        float f0b = act ? feat_nt(featp, (long long)(v0 + 1) * DD + lane, ft) : 0.0f;
        float f0c = act ? feat_nt(featp, (long long)(v0 + 2) * DD + lane, ft) : 0.0f;
        float f0d = act ? feat_nt(featp, (long long)(v0 + 3) * DD + lane, ft) : 0.0f;

        int wbase = b0;
        int my = ((b0 + lane) < EE) ? __builtin_nontemporal_load(col_idx + b0 + lane) : 0;
        int wend = b0 + 64;
        int posi = b0;
        float s0 = 0.0f, s1 = 0.0f, s2 = 0.0f, s3 = 0.0f;

#define SEG(ENDK, F0, KI) { \
        while (posi < (ENDK)) { \
            if (posi >= wend) { \
                wbase = posi; wend = posi + 64; \
                my = ((posi + lane) < EE) ? __builtin_nontemporal_load(col_idx + posi + lane) : 0; \
            } \
            int lim = (ENDK) < wend ? (ENDK) : wend; \
            int take = lim - posi; take = take > 8 ? 8 : take; \
            int rel = posi - wbase; \
            int c0 = __shfl(my, rel, 64); \
            int c1 = __shfl(my, rel + (take > 1 ? 1 : 0), 64); \
            int c2 = __shfl(my, rel + (take > 2 ? 2 : 0), 64); \
            int c3 = __shfl(my, rel + (take > 3 ? 3 : 0), 64); \
            int c4 = __shfl(my, rel + (take > 4 ? 4 : 0), 64); \
            int c5 = __shfl(my, rel + (take > 5 ? 5 : 0), 64); \
            int c6 = __shfl(my, rel + (take > 6 ? 6 : 0), 64); \
            int c7 = __shfl(my, rel + (take > 7 ? 7 : 0), 64); \
            float x0 = bf16_ld(gin, (c0 << 6) + lane); \
            float x1 = bf16_ld(gin, (c1 << 6) + lane); \
            float x2 = bf16_ld(gin, (c2 << 6) + lane); \
            float x3 = bf16_ld(gin, (c3 << 6) + lane); \
            float x4 = bf16_ld(gin, (c4 << 6) + lane); \
            float x5 = bf16_ld(gin, (c5 << 6) + lane); \
            float x6 = bf16_ld(gin, (c6 << 6) + lane); \
            float x7 = bf16_ld(gin, (c7 << 6) + lane); \
            s0 += x0; \
            s1 += (take > 1) ? x1 : 0.0f; \
            s2 += (take > 2) ? x2 : 0.0f; \
            s3 += (take > 3) ? x3 : 0.0f; \
            s0 += (take > 4) ? x4 : 0.0f; \
            s1 += (take > 5) ? x5 : 0.0f; \
            s2 += (take > 6) ? x6 : 0.0f; \
            s3 += (take > 7) ? x7 : 0.0f; \
            posi += take; \
        } \
        { \
            float sum = (s0 + s1) + (s2 + s3); \
            s0 = 0.0f; s1 = 0.0f; s2 = 0.0f; s3 = 0.0f; \
            float nv = __shfl(nl, KI, 64); \
            float res = 0.9f * (sum * nv) + 0.1f * (F0); \
            if (last) { \
                if (act) outp[(long long)(v0 + KI) * DD + lane] = res; \
            } else { \
                unsigned short st = act ? bf16_st(res * nv) : (unsigned short)0; \
                gout[((v0 + KI) << 6) + lane] = st; \
            } \
        } }

        SEG(b1, f0a, 0)
        SEG(b2, f0b, 1)
        SEG(b3, f0c, 2)
        SEG(b4, f0d, 3)
#undef SEG
    }
}

extern "C" void kernel_launch(void* const* d_in, const int* in_sizes, int n_in,
                              void* d_out, int out_size, void* d_ws, size_t ws_size,
                              hipStream_t stream) {
    const void* featp = d_in[0];
    const void* src = d_in[1];
    const void* dst = d_in[2];
    float* outf = (float*)d_out;
    unsigned short* P_do = (unsigned short*)d_out;   // padded plane in d_out (12.8 MB)
    unsigned int* counts = (unsigned int*)d_out;     // 12.8 MB (build only)
    size_t out_bytes = (size_t)out_size * 4;
    (void)in_sizes;

    if (n_in != 3) {
        hipMemsetAsync(d_out, 0x50, out_bytes, stream);
        return;
    }

    size_t a_deg  = (((size_t)NN * 4) + 255) / 256 * 256;
    size_t a_norm = a_deg;
    size_t a_rp   = (((size_t)(NN + 1) * 4) + 255) / 256 * 256;
    size_t a_col  = (((size_t)EE * 4) + 255) / 256 * 256;
    size_t a_bsum = (((size_t)NBLK * 4) + 255) / 256 * 256;
    size_t a_flag = 256;
    size_t a_buf  = (((size_t)NN * GS * 2) + 255) / 256 * 256; // 12.8 MB padded plane
    if (ws_size < a_deg + a_norm + a_rp + a_col + a_bsum + a_flag + a_buf ||
        out_bytes < (size_t)SLICES * NN * 4) {
        hipMemsetAsync(d_out, 0x40, out_bytes, stream);
        return;
    }
    char* p = (char*)d_ws;
    int* deg      = (int*)p;   p += a_deg;
    float* norm   = (float*)p; p += a_norm;
    int* row_ptr  = (int*)p;   p += a_rp;
    int* col_idx  = (int*)p;   p += a_col;
    int* bsum     = (int*)p;   p += a_bsum;
    int* flag     = (int*)p;   p += a_flag;
    unsigned short* P_ws = (unsigned short*)p;

    (void)hipGetLastError();

    #define LCH(grid, blk, gi, go, ph, la) \
        APPNPConv_62199716381208_kernel<<<(grid), (blk), 0, stream>>>( \
            featp, src, dst, deg, norm, row_ptr, col_idx, bsum, flag, counts, \
            (gi), (go), outf, (ph), (la))
    #define LCB(ph) \
        APPNPConv_62199716381208_build<<<SLICES * RANGES, 512, 0, stream>>>( \
            src, dst, featp, counts, col_idx, flag, (ph))

    LCB(0);                                           // phA: flags + LDS-hist counts
    LCH(NBLK, 256, P_ws, P_ws, 2, 0);                 // totals + norm
    LCH(1, 512, P_ws, P_ws, 3, 0);                    // scan
    LCH(NBLK, 256, P_ws, P_ws, 4, 0);                 // row_ptr + slice bases
    LCB(1);                                           // phC: LDS-cursor scatter
    LCH((NN * GS + 255) / 256, 256, P_ws, P_do, 6, 0); // g0 -> P_do (zero-padded)

    // it odd: P_do -> P_ws ; it even: P_ws -> P_do.
    // it10 (even): reads P_ws, writes FINAL fp32 over all of d_out.
    for (int it = 1; it <= KK; ++it) {
        const unsigned short* gi = (it & 1) ? P_do : P_ws;
        unsigned short* go       = (it & 1) ? P_ws : P_do;
        LCH(NN / 16, 256, gi, go, 7, (it == KK) ? 1 : 0);
    }
    #undef LCH
    #undef LCB

    if (hipGetLastError() != hipSuccess) {
        hipMemsetAsync(d_out, 0xBF, out_bytes, stream);
    }
}